// Round 4
// baseline (765.761 us; speedup 1.0000x reference)
//
#include <hip/hip_runtime.h>
#include <math.h>

// GCN 2-layer, N=100000, E=6400000, Fin=1, Fhid=16, Fout=2.
// R18: R14's proven 4-edge-pass pipeline (233us) with node kernels fused
// into the edge passes via the rocPRIM "last block per bucket" pattern.
// Established walls (R14-R17 + rocprof):
//   - ANY per-edge op costs ~4.6 cyc/CU/edge (LDS atomic / random gather /
//     scattered write); pipes overlap within a pass; the dinv dependency
//     chain forces 4 passes -> ~192us edge-wall floor.
//   - Per-edge GLOBAL atomics are memory-side: 229MB WRITE_SIZE, +214us
//     (R16). Per-BUCKET ticket atomics here = 784 total = harmless.
//   - Cooperative grid.sync fusion runs phases 2.3x slower (R17: 535us;
//     lockstep stragglers, 2x bank conflicts, no inter-phase overlap).
// R18 recovers the ~41us of non-wall overhead (3 node kernels + 6 launch
// gaps) without lockstep: the 8 split-blocks of bucket b write partials,
// __threadfence(), atomicAdd ticket[b]; the 8th block sums partials and
// runs the node math inline while other buckets' edge work continues.
//   1. k_place : LDS cursor place into (bucket, blk) cells.       ~48us
//   2. k_degN  : deg partials + last-block {dinv=rsqrt(deg+1), y=dinv*x}
//   3. k_agg1N : layer-1 partials (LDS acc + gather y[src]) +
//                last-block {1->16 relu MLP -> dlt = dinv*(g1-g0)}
//   4. k_agg2N : layer-2 partials over dlt + last-block {2-class
//                log_softmax from d = z1-z0 -> out}
// word = (dst&1023)<<17 | src  (src < 2^17).

#define CSH   10
#define CMASK 1023
#define C     1024
#define B1P   256      // place blocks; chunk = E/B1P = 25000 (/4 exact)
#define CAP   384      // slots per (bucket, block) cell (mean 255, +8sigma)
#define S     8        // splits per bucket in edge passes
#define AT    512      // threads for edge passes

// --- pass 1: sparse counting place (R11/R14-proven, verbatim)
__global__ __launch_bounds__(256) void k_place(const int* __restrict__ src,
                                               const int* __restrict__ dst,
                                               int* __restrict__ sparse,
                                               int* __restrict__ G,
                                               int chunk, int nbkt) {
    __shared__ int cur[128];
    int t = threadIdx.x, blk = blockIdx.x;
    if (t < nbkt) cur[t] = t * (B1P * CAP) + blk * CAP;
    __syncthreads();
    int s0 = blk * chunk, n4 = chunk >> 2;
    const int4* d4 = (const int4*)(dst + s0);
    const int4* s4 = (const int4*)(src + s0);
    for (int i = t; i < n4; i += 256) {
        int4 d = d4[i];
        int4 s = s4[i];
        int b, q;
        b = d.x >> CSH; q = atomicAdd(&cur[b], 1);
        if (q < b * (B1P * CAP) + blk * CAP + CAP) sparse[q] = ((d.x & CMASK) << 17) | s.x;
        b = d.y >> CSH; q = atomicAdd(&cur[b], 1);
        if (q < b * (B1P * CAP) + blk * CAP + CAP) sparse[q] = ((d.y & CMASK) << 17) | s.y;
        b = d.z >> CSH; q = atomicAdd(&cur[b], 1);
        if (q < b * (B1P * CAP) + blk * CAP + CAP) sparse[q] = ((d.z & CMASK) << 17) | s.z;
        b = d.w >> CSH; q = atomicAdd(&cur[b], 1);
        if (q < b * (B1P * CAP) + blk * CAP + CAP) sparse[q] = ((d.w & CMASK) << 17) | s.w;
    }
    __syncthreads();
    if (t < nbkt) {
        int cnt = cur[t] - (t * (B1P * CAP) + blk * CAP);
        G[t * B1P + blk] = (cnt < CAP) ? cnt : CAP;
    }
}

// --- pass 2: per-node degree partials + last-block node1 (dinv, y)
__global__ __launch_bounds__(AT) void k_degN(const int* __restrict__ sparse,
                                             const int* __restrict__ G,
                                             const float* __restrict__ x,
                                             int* __restrict__ Pdeg,
                                             float* __restrict__ dinv,
                                             float* __restrict__ y,
                                             int* __restrict__ tick, int N) {
    __shared__ int cnt[C];
    __shared__ int lastFlag;
    int t = threadIdx.x, g = blockIdx.x;
    int b = g >> 3, s = g & 7;
    cnt[t] = 0; cnt[t + AT] = 0;
    __syncthreads();
    int wave = t >> 6, lane = t & 63;
#pragma unroll
    for (int k = 0; k < 4; k++) {
        int blk = (s << 5) + wave + (k << 3);   // s*32 + wave + 8k
        int r = b * B1P + blk;
        int cr = G[r];
        int base = r * CAP;
        for (int i = lane; i < cr; i += 64)
            atomicAdd(&cnt[sparse[base + i] >> 17], 1);
    }
    __syncthreads();
    Pdeg[(size_t)g * C + t] = cnt[t];
    Pdeg[(size_t)g * C + t + AT] = cnt[t + AT];
    // --- last-block-per-bucket fusion of node1
    __threadfence();
    __syncthreads();
    if (t == 0) lastFlag = (atomicAdd(&tick[b], 1) == S - 1);
    __syncthreads();
    if (!lastFlag) return;
    __threadfence();
    const int* pb = Pdeg + (size_t)(b * S) * C;
    for (int n = t; n < C; n += AT) {
        int node = (b << CSH) + n;
        if (node < N) {
            int deg = 0;
#pragma unroll
            for (int s2 = 0; s2 < S; s2++) deg += pb[(size_t)s2 * C + n];
            float di = rsqrtf((float)deg + 1.0f);   // +1 self-loop
            dinv[node] = di;
            y[node] = di * x[node];
        }
    }
}

// --- pass 3: layer-1 partials (LDS acc + gather y[src]) + last-block
//     node2 (1->16 relu MLP -> dlt = dinv*(g1-g0); log_softmax needs z1-z0)
__global__ __launch_bounds__(AT) void k_agg1N(const int* __restrict__ sparse,
                                              const int* __restrict__ G,
                                              const float* __restrict__ y,
                                              const float* __restrict__ dinv,
                                              const float* __restrict__ W1,
                                              const float* __restrict__ b1,
                                              const float* __restrict__ W2,
                                              float* __restrict__ P1,
                                              float* __restrict__ dlt,
                                              int* __restrict__ tick, int N) {
    __shared__ float acc[C];
    __shared__ int lastFlag;
    int t = threadIdx.x, g = blockIdx.x;
    int b = g >> 3, s = g & 7;
    acc[t] = 0.f; acc[t + AT] = 0.f;
    __syncthreads();
    int wave = t >> 6, lane = t & 63;
#pragma unroll
    for (int k = 0; k < 4; k++) {
        int blk = (s << 5) + wave + (k << 3);
        int r = b * B1P + blk;
        int cr = G[r];
        int base = r * CAP;
        for (int i = lane; i < cr; i += 64) {
            int p = sparse[base + i];
            atomicAdd(&acc[p >> 17], y[p & 0x1FFFF]);
        }
    }
    __syncthreads();
    P1[(size_t)g * C + t] = acc[t];
    P1[(size_t)g * C + t + AT] = acc[t + AT];
    // --- last-block-per-bucket fusion of node2
    __threadfence();
    __syncthreads();
    if (t == 0) lastFlag = (atomicAdd(&tick[b], 1) == S - 1);
    __syncthreads();
    if (!lastFlag) return;
    __threadfence();
    const float* pb = P1 + (size_t)(b * S) * C;
    for (int n = t; n < C; n += AT) {
        int node = (b << CSH) + n;
        if (node < N) {
            float sum = 0.f;
#pragma unroll
            for (int s2 = 0; s2 < S; s2++) sum += pb[(size_t)s2 * C + n];
            float di = dinv[node];
            float Sv = di * (sum + y[node]);        // self-loop adds y[node]
            float g0 = 0.f, g1 = 0.f;
#pragma unroll
            for (int f = 0; f < 16; f++) {
                float h = fmaxf(fmaf(W1[f], Sv, b1[f]), 0.f);
                g0 = fmaf(h, W2[2 * f], g0);
                g1 = fmaf(h, W2[2 * f + 1], g1);
            }
            dlt[node] = di * (g1 - g0);             // premultiplied by dinv[src]
        }
    }
}

// --- pass 4: layer-2 partials over dlt + last-block out (stable 2-class
//     log_softmax from the difference alone)
__global__ __launch_bounds__(AT) void k_agg2N(const int* __restrict__ sparse,
                                              const int* __restrict__ G,
                                              const float* __restrict__ dlt,
                                              const float* __restrict__ dinv,
                                              const float* __restrict__ b2,
                                              float* __restrict__ P2,
                                              float2* __restrict__ out,
                                              int* __restrict__ tick, int N) {
    __shared__ float acc[C];
    __shared__ int lastFlag;
    int t = threadIdx.x, g = blockIdx.x;
    int b = g >> 3, s = g & 7;
    acc[t] = 0.f; acc[t + AT] = 0.f;
    __syncthreads();
    int wave = t >> 6, lane = t & 63;
#pragma unroll
    for (int k = 0; k < 4; k++) {
        int blk = (s << 5) + wave + (k << 3);
        int r = b * B1P + blk;
        int cr = G[r];
        int base = r * CAP;
        for (int i = lane; i < cr; i += 64) {
            int p = sparse[base + i];
            atomicAdd(&acc[p >> 17], dlt[p & 0x1FFFF]);
        }
    }
    __syncthreads();
    P2[(size_t)g * C + t] = acc[t];
    P2[(size_t)g * C + t + AT] = acc[t + AT];
    // --- last-block-per-bucket fusion of k_out
    __threadfence();
    __syncthreads();
    if (t == 0) lastFlag = (atomicAdd(&tick[b], 1) == S - 1);
    __syncthreads();
    if (!lastFlag) return;
    __threadfence();
    const float* pb = P2 + (size_t)(b * S) * C;
    float db2 = b2[1] - b2[0];
    for (int n = t; n < C; n += AT) {
        int node = (b << CSH) + n;
        if (node < N) {
            float sum = 0.f;
#pragma unroll
            for (int s2 = 0; s2 < S; s2++) sum += pb[(size_t)s2 * C + n];
            float d = dinv[node] * (sum + dlt[node]) + db2;   // z1 - z0
            float o0, o1;
            if (d > 0.f) {
                float e = expf(-d);
                o0 = -d - log1pf(e);
                o1 = -log1pf(e);
            } else {
                float e = expf(d);
                o0 = -log1pf(e);
                o1 = d - log1pf(e);
            }
            out[node] = make_float2(o0, o1);
        }
    }
}

extern "C" void kernel_launch(void* const* d_in, const int* in_sizes, int n_in,
                              void* d_out, int out_size, void* d_ws, size_t ws_size,
                              hipStream_t stream) {
    const float* x  = (const float*)d_in[0];
    const int* ei   = (const int*)d_in[1];
    const float* W1 = (const float*)d_in[2];
    const float* b1 = (const float*)d_in[3];
    const float* W2 = (const float*)d_in[4];
    const float* b2 = (const float*)d_in[5];

    const int N = in_sizes[0];        // 100000
    const int E = in_sizes[1] / 2;    // 6400000
    const int* src = ei;
    const int* dst = ei + E;

    const int nbkt  = (N + CMASK) >> CSH;    // 98
    const int chunk = E / B1P;               // 25000
    const int NREG  = nbkt * B1P;            // 25088 cells
    const int gF    = nbkt * S;              // 784 edge-pass blocks
    const int np    = nbkt << CSH;           // 100352 padded nodes

    // ws (ints): sparse[NREG*CAP] 38.5MB | G[NREG] | Pbuf[gF*C] 3.2MB |
    //            dinv[np] | y[np] | dlt[np] | tick[3*128]   (~44 MB)
    // Pbuf reused: Pdeg(int) -> P1(float) -> P2(float); each fully consumed
    // by its own last-blocks before the next edge pass overwrites it
    // (kernel boundary = full device sync in stream order).
    int* sparse = (int*)d_ws;
    int* G      = sparse + (size_t)NREG * CAP;
    int* Pbuf   = G + NREG;
    float* dinv = (float*)(Pbuf + (size_t)gF * C);
    float* y    = dinv + np;
    float* dlt  = y + np;
    int* tick   = (int*)(dlt + np);          // 3 arrays of 128 ints

    hipMemsetAsync(tick, 0, 3 * 128 * sizeof(int), stream);
    k_place <<<B1P, 256, 0, stream>>>(src, dst, sparse, G, chunk, nbkt);
    k_degN  <<<gF,  AT,  0, stream>>>(sparse, G, x, Pbuf, dinv, y, tick, N);
    k_agg1N <<<gF,  AT,  0, stream>>>(sparse, G, y, dinv, W1, b1, W2,
                                      (float*)Pbuf, dlt, tick + 128, N);
    k_agg2N <<<gF,  AT,  0, stream>>>(sparse, G, dlt, dinv, b2,
                                      (float*)Pbuf, (float2*)d_out, tick + 256, N);
}

// Round 5
// 225.010 us; speedup vs baseline: 3.4032x; 3.4032x over previous
//
#include <hip/hip_runtime.h>
#include <math.h>

// GCN 2-layer, N=100000, E=6400000, Fin=1, Fhid=16, Fout=2.
// R19: R14's proven 4-pass pipeline (233us, reproduced) with ONE change:
// the deg/agg edge passes run 768 blocks (= exactly 3 per CU) instead of
// 784 (= 3.06/CU). With VGPR=8 / LDS=4KB all blocks co-reside; at 784,
// 16 CUs carry 4 blocks (+33% work) and set the pass time while 240 CUs
// idle the tail -> ~12us/pass of recoverable imbalance.
// Mapping: 82 buckets x 8 splits + 16 buckets x 7 splits = 768 blocks
// (per-block work varies only +-14%).
// Hard-won DON'Ts (R15-R18, all regressed, counters on file):
//   - per-edge global atomics: memory-side, ~36B WRITE each (R16: +229MB,
//     +214us). Per-BUCKET/none only.
//   - cooperative grid.sync mega-kernel: phases 2.3x slower (R17, lockstep
//     stragglers + 2x LDS conflicts).
//   - __threadfence() in edge passes: device-scope fence = L2 writeback
//     across 8 non-coherent XCDs; 784 of them under load = pass x5.6
//     (R18). Blocks must stay independent; sync = kernel boundary only.
//   - CSR restructure: standalone gather pass has its own ~4.6cyc/edge
//     wall; 448B cells double place's WRITE_SIZE (R15).
// Established wall: ANY per-edge op costs ~4.6 cyc/CU/edge on its pipe
// (LDS atomic / random gather / scattered write); different pipes overlap
// within one pass; the dinv dependency chain forces 4 passes.
// word = (dst&1023)<<17 | src  (src < 2^17).

#define CSH   10
#define CMASK 1023
#define C     1024
#define B1P   256      // place blocks; chunk = E/B1P = 25000 (/4 exact)
#define CAP   384      // slots per (bucket, block) cell (mean 255, +8sigma)
#define GF    768      // deg/agg blocks: exactly 3 per CU
#define AT    512      // threads for deg/agg

// --- pass 1: sparse counting place (R11/R14-proven, verbatim)
__global__ __launch_bounds__(256) void k_place(const int* __restrict__ src,
                                               const int* __restrict__ dst,
                                               int* __restrict__ sparse,
                                               int* __restrict__ G,
                                               int chunk, int nbkt) {
    __shared__ int cur[128];
    int t = threadIdx.x, blk = blockIdx.x;
    if (t < nbkt) cur[t] = t * (B1P * CAP) + blk * CAP;
    __syncthreads();
    int s0 = blk * chunk, n4 = chunk >> 2;
    const int4* d4 = (const int4*)(dst + s0);
    const int4* s4 = (const int4*)(src + s0);
    for (int i = t; i < n4; i += 256) {
        int4 d = d4[i];
        int4 s = s4[i];
        int b, q;
        b = d.x >> CSH; q = atomicAdd(&cur[b], 1);
        if (q < b * (B1P * CAP) + blk * CAP + CAP) sparse[q] = ((d.x & CMASK) << 17) | s.x;
        b = d.y >> CSH; q = atomicAdd(&cur[b], 1);
        if (q < b * (B1P * CAP) + blk * CAP + CAP) sparse[q] = ((d.y & CMASK) << 17) | s.y;
        b = d.z >> CSH; q = atomicAdd(&cur[b], 1);
        if (q < b * (B1P * CAP) + blk * CAP + CAP) sparse[q] = ((d.z & CMASK) << 17) | s.z;
        b = d.w >> CSH; q = atomicAdd(&cur[b], 1);
        if (q < b * (B1P * CAP) + blk * CAP + CAP) sparse[q] = ((d.w & CMASK) << 17) | s.w;
    }
    __syncthreads();
    if (t < nbkt) {
        int cnt = cur[t] - (t * (B1P * CAP) + blk * CAP);
        G[t * B1P + blk] = (cnt < CAP) ? cnt : CAP;
    }
}

// block g -> (bucket b, split s, nsplits Sb). First `rem` buckets have
// q+1 splits, the rest q.  (q=7, rem=82 for N=100000 -> GF=768.)
__device__ __forceinline__ void blk_map(int g, int q, int rem,
                                        int& b, int& s, int& Sb) {
    int cut = rem * (q + 1);
    if (g < cut) { b = g / (q + 1); s = g - b * (q + 1); Sb = q + 1; }
    else { int h = g - cut; b = rem + h / q; s = h - (h / q) * q; Sb = q; }
}

// --- per-node degree partials over bucket b's cells (split s: c = s+m*Sb)
__global__ __launch_bounds__(AT) void k_deg(const int* __restrict__ sparse,
                                            const int* __restrict__ G,
                                            int* __restrict__ Pdeg,
                                            int q, int rem) {
    __shared__ int cnt[C];
    int t = threadIdx.x, g = blockIdx.x;
    int b, s, Sb; blk_map(g, q, rem, b, s, Sb);
    cnt[t] = 0; cnt[t + AT] = 0;
    __syncthreads();
    int wave = t >> 6, lane = t & 63;
    for (int m = wave;; m += 8) {
        int c = s + m * Sb;
        if (c >= B1P) break;
        int r = b * B1P + c;
        int cr = G[r];
        int base = r * CAP;
        for (int i = lane; i < cr; i += 64)
            atomicAdd(&cnt[sparse[base + i] >> 17], 1);
    }
    __syncthreads();
    Pdeg[(size_t)g * C + t] = cnt[t];
    Pdeg[(size_t)g * C + t + AT] = cnt[t + AT];
}

// --- nodes: deg -> dinv, y = dinv * x
__global__ __launch_bounds__(256) void k_node1(const int* __restrict__ Pdeg,
                                               const float* __restrict__ x,
                                               float* __restrict__ dinv,
                                               float* __restrict__ y,
                                               int q, int rem, int N) {
    int node = blockIdx.x * 256 + threadIdx.x;
    if (node >= N) return;
    int b = node >> CSH, l = node & CMASK;
    int off = (b < rem) ? b * (q + 1) : rem * (q + 1) + (b - rem) * q;
    int cnt = (b < rem) ? q + 1 : q;
    const int* base = Pdeg + (size_t)off * C + l;
    int deg = 0;
    for (int s = 0; s < cnt; s++) deg += base[(size_t)s * C];
    float di = rsqrtf((float)deg + 1.0f);   // +1 self-loop
    dinv[node] = di;
    y[node] = di * x[node];
}

// --- layer-1 partial sums: LDS float acc + gather y[src]
__global__ __launch_bounds__(AT) void k_agg1(const int* __restrict__ sparse,
                                             const int* __restrict__ G,
                                             const float* __restrict__ y,
                                             float* __restrict__ P1,
                                             int q, int rem) {
    __shared__ float acc[C];
    int t = threadIdx.x, g = blockIdx.x;
    int b, s, Sb; blk_map(g, q, rem, b, s, Sb);
    acc[t] = 0.f; acc[t + AT] = 0.f;
    __syncthreads();
    int wave = t >> 6, lane = t & 63;
    for (int m = wave;; m += 8) {
        int c = s + m * Sb;
        if (c >= B1P) break;
        int r = b * B1P + c;
        int cr = G[r];
        int base = r * CAP;
        for (int i = lane; i < cr; i += 64) {
            int p = sparse[base + i];
            atomicAdd(&acc[p >> 17], y[p & 0x1FFFF]);
        }
    }
    __syncthreads();
    P1[(size_t)g * C + t] = acc[t];
    P1[(size_t)g * C + t + AT] = acc[t + AT];
}

// --- nodes: layer-1 finish + fused 1->16 relu MLP -> 16->2, emit scalar
//     delta[node] = dinv * (g1 - g0)   (log_softmax needs only z1-z0)
__global__ __launch_bounds__(256) void k_node2(const float* __restrict__ P1,
                                               const float* __restrict__ dinv,
                                               const float* __restrict__ y,
                                               const float* __restrict__ W1,
                                               const float* __restrict__ b1,
                                               const float* __restrict__ W2,
                                               float* __restrict__ dlt,
                                               int q, int rem, int N) {
    int node = blockIdx.x * 256 + threadIdx.x;
    if (node >= N) return;
    int b = node >> CSH, l = node & CMASK;
    int off = (b < rem) ? b * (q + 1) : rem * (q + 1) + (b - rem) * q;
    int cnt = (b < rem) ? q + 1 : q;
    const float* base = P1 + (size_t)off * C + l;
    float sum = 0.f;
    for (int s = 0; s < cnt; s++) sum += base[(size_t)s * C];
    float di = dinv[node];
    float Sv = di * (sum + y[node]);        // self-loop adds y[node]
    float g0 = 0.f, g1 = 0.f;
#pragma unroll
    for (int f = 0; f < 16; f++) {
        float h = fmaxf(fmaf(W1[f], Sv, b1[f]), 0.f);
        g0 = fmaf(h, W2[2 * f], g0);
        g1 = fmaf(h, W2[2 * f + 1], g1);
    }
    dlt[node] = di * (g1 - g0);             // premultiplied by dinv[src]
}

// --- layer-2 partial sums of the scalar delta
__global__ __launch_bounds__(AT) void k_agg2d(const int* __restrict__ sparse,
                                              const int* __restrict__ G,
                                              const float* __restrict__ dlt,
                                              float* __restrict__ P2,
                                              int q, int rem) {
    __shared__ float acc[C];
    int t = threadIdx.x, g = blockIdx.x;
    int b, s, Sb; blk_map(g, q, rem, b, s, Sb);
    acc[t] = 0.f; acc[t + AT] = 0.f;
    __syncthreads();
    int wave = t >> 6, lane = t & 63;
    for (int m = wave;; m += 8) {
        int c = s + m * Sb;
        if (c >= B1P) break;
        int r = b * B1P + c;
        int cr = G[r];
        int base = r * CAP;
        for (int i = lane; i < cr; i += 64) {
            int p = sparse[base + i];
            atomicAdd(&acc[p >> 17], dlt[p & 0x1FFFF]);
        }
    }
    __syncthreads();
    P2[(size_t)g * C + t] = acc[t];
    P2[(size_t)g * C + t + AT] = acc[t + AT];
}

// --- nodes: d = di*(sum + delta_self) + (b2[1]-b2[0]); stable 2-class
//     log_softmax from the difference alone
__global__ __launch_bounds__(256) void k_out(const float* __restrict__ P2,
                                             const float* __restrict__ dinv,
                                             const float* __restrict__ dlt,
                                             const float* __restrict__ b2,
                                             float2* __restrict__ out,
                                             int q, int rem, int N) {
    int node = blockIdx.x * 256 + threadIdx.x;
    if (node >= N) return;
    int b = node >> CSH, l = node & CMASK;
    int off = (b < rem) ? b * (q + 1) : rem * (q + 1) + (b - rem) * q;
    int cnt = (b < rem) ? q + 1 : q;
    const float* base = P2 + (size_t)off * C + l;
    float sum = 0.f;
    for (int s = 0; s < cnt; s++) sum += base[(size_t)s * C];
    float d = dinv[node] * (sum + dlt[node]) + (b2[1] - b2[0]);  // z1 - z0
    float o0, o1;
    if (d > 0.f) {
        float e = expf(-d);
        o0 = -d - log1pf(e);
        o1 = -log1pf(e);
    } else {
        float e = expf(d);
        o0 = -log1pf(e);
        o1 = d - log1pf(e);
    }
    out[node] = make_float2(o0, o1);
}

extern "C" void kernel_launch(void* const* d_in, const int* in_sizes, int n_in,
                              void* d_out, int out_size, void* d_ws, size_t ws_size,
                              hipStream_t stream) {
    const float* x  = (const float*)d_in[0];
    const int* ei   = (const int*)d_in[1];
    const float* W1 = (const float*)d_in[2];
    const float* b1 = (const float*)d_in[3];
    const float* W2 = (const float*)d_in[4];
    const float* b2 = (const float*)d_in[5];

    const int N = in_sizes[0];        // 100000
    const int E = in_sizes[1] / 2;    // 6400000
    const int* src = ei;
    const int* dst = ei + E;

    const int nbkt  = (N + CMASK) >> CSH;    // 98
    const int chunk = E / B1P;               // 25000
    const int NREG  = nbkt * B1P;            // 25088 cells
    const int np    = nbkt << CSH;           // 100352 padded nodes
    const int gN    = (N + 255) / 256;       // 391

    // variable-split mapping: rem buckets get q+1 splits, rest get q;
    // total blocks = GF = 768 (exactly 3/CU).  q=7, rem=82 for nbkt=98.
    const int q   = GF / nbkt;               // 7
    const int rem = GF - nbkt * q;           // 82

    // ws (ints): sparse[NREG*CAP] 38.5MB | G[NREG] | Pbuf[GF*C] 3.1MB |
    //            dinv[np] | y[np] | dlt[np]   (~43 MB)
    // Pbuf reused: Pdeg(int) -> P1(float) -> P2(float); each fully consumed
    // by the following node pass before the next edge pass overwrites it.
    int* sparse = (int*)d_ws;
    int* G      = sparse + (size_t)NREG * CAP;
    int* Pbuf   = G + NREG;
    float* dinv = (float*)(Pbuf + (size_t)GF * C);
    float* y    = dinv + np;
    float* dlt  = y + np;

    k_place <<<B1P, 256, 0, stream>>>(src, dst, sparse, G, chunk, nbkt);
    k_deg   <<<GF,  AT,  0, stream>>>(sparse, G, Pbuf, q, rem);
    k_node1 <<<gN,  256, 0, stream>>>(Pbuf, x, dinv, y, q, rem, N);
    k_agg1  <<<GF,  AT,  0, stream>>>(sparse, G, y, (float*)Pbuf, q, rem);
    k_node2 <<<gN,  256, 0, stream>>>((const float*)Pbuf, dinv, y, W1, b1, W2,
                                      dlt, q, rem, N);
    k_agg2d <<<GF,  AT,  0, stream>>>(sparse, G, dlt, (float*)Pbuf, q, rem);
    k_out   <<<gN,  256, 0, stream>>>((const float*)Pbuf, dinv, dlt, b2,
                                      (float2*)d_out, q, rem, N);
}